// Round 1
// baseline (403.254 us; speedup 1.0000x reference)
//
#include <hip/hip_runtime.h>
#include <hip/hip_bf16.h>

#define B_ 8
#define T_ 4096
#define D_ 1024
#define H_ 1024

typedef __attribute__((ext_vector_type(8))) short short8;
typedef __attribute__((ext_vector_type(4))) float floatx4;

#define GLOAD16(gptr, lptr) \
  __builtin_amdgcn_global_load_lds((const __attribute__((address_space(1))) void*)(gptr), \
                                   (__attribute__((address_space(3))) void*)(lptr), 16, 0, 0)

__device__ __forceinline__ ushort f2b(float f) {
  unsigned x = __builtin_bit_cast(unsigned, f);
  unsigned r = (x + 0x7fffu + ((x >> 16) & 1u)) >> 16;  // RNE, inputs finite
  return (ushort)r;
}

__global__ void cvt_kernel(const float* __restrict__ in, ushort* __restrict__ out, int n) {
  int idx = blockIdx.x * blockDim.x + threadIdx.x;
  int stride = gridDim.x * blockDim.x;
  for (long i = (long)idx * 8; i < n; i += (long)stride * 8) {
    const float4 f0 = *(const float4*)(in + i);
    const float4 f1 = *(const float4*)(in + i + 4);
    union { ushort u[8]; uint4 v; } r;
    r.u[0] = f2b(f0.x); r.u[1] = f2b(f0.y); r.u[2] = f2b(f0.z); r.u[3] = f2b(f0.w);
    r.u[4] = f2b(f1.x); r.u[5] = f2b(f1.y); r.u[6] = f2b(f1.z); r.u[7] = f2b(f1.w);
    *(uint4*)(out + i) = r.v;
  }
}

// K1: fused K/V GEMM + batch reduction.
// Block = 128 t-rows x 128 h-cols, loops b=0..7, accumulates
// sumN = sum_b exp(K+bk+wbias), sumWV = sum_b exp(...)*(V+bv) in registers,
// writes weighted[t,h] = sumWV/sumN.
__global__ __launch_bounds__(512, 2) void kv_kernel(
    const ushort* __restrict__ xb, const ushort* __restrict__ Wkb,
    const ushort* __restrict__ Wvb, const float* __restrict__ bk,
    const float* __restrict__ bv, const float* __restrict__ wbias,
    float* __restrict__ weighted) {
  __shared__ ushort As[128 * 32];
  __shared__ ushort Ks[128 * 32];
  __shared__ ushort Vs[128 * 32];

  const int tid = threadIdx.x;
  const int lane = tid & 63;
  const int w = tid >> 6;       // 0..7
  const int wrow = w >> 2;      // 0..1  (64-row granule)
  const int wcol = w & 3;       // 0..3  (32-col granule)
  const int h0 = blockIdx.x * 128;
  const int t0 = blockIdx.y * 128;

  // staging: 512 slots of 16B per 8KiB tile, slot = tid
  const int srow = tid >> 2;         // 0..127
  const int scol = (tid & 3) * 8;    // 0,8,16,24

  // fragment addressing (mfma_f32_16x16x32_bf16):
  // A: row = lane&15 (+m*16), k = (lane>>4)*8 + j
  // B: col = lane&15 (+n*16), k = (lane>>4)*8 + j
  const int arow = wrow * 64 + (lane & 15);
  const int bcol = wcol * 32 + (lane & 15);
  const int koff = (lane >> 4) * 8;

  float wbc[2], bkc[2], bvc[2];
#pragma unroll
  for (int n = 0; n < 2; ++n) {
    int h = h0 + wcol * 32 + n * 16 + (lane & 15);
    wbc[n] = wbias[h];
    bkc[n] = bk[h];
    bvc[n] = bv[h];
  }

  floatx4 sumN[4][2] = {};
  floatx4 sumWV[4][2] = {};

  const ushort* kwbase = Wkb + (size_t)h0 * D_;
  const ushort* vwbase = Wvb + (size_t)h0 * D_;

  for (int b = 0; b < B_; ++b) {
    floatx4 accK[4][2] = {};
    floatx4 accV[4][2] = {};
    const ushort* xbase = xb + ((size_t)(b * T_ + t0)) * D_;
    for (int kt = 0; kt < D_; kt += 32) {
      __syncthreads();  // prior compute done before LDS overwrite
      GLOAD16(xbase + (size_t)srow * D_ + kt + scol, As + tid * 8);
      GLOAD16(kwbase + (size_t)srow * D_ + kt + scol, Ks + tid * 8);
      GLOAD16(vwbase + (size_t)srow * D_ + kt + scol, Vs + tid * 8);
      __syncthreads();  // drains vmcnt: staged data visible

      short8 a[4], kb[2], vb[2];
#pragma unroll
      for (int m = 0; m < 4; ++m)
        a[m] = *(const short8*)&As[(arow + m * 16) * 32 + koff];
#pragma unroll
      for (int n = 0; n < 2; ++n) {
        kb[n] = *(const short8*)&Ks[(bcol + n * 16) * 32 + koff];
        vb[n] = *(const short8*)&Vs[(bcol + n * 16) * 32 + koff];
      }
#pragma unroll
      for (int m = 0; m < 4; ++m)
#pragma unroll
        for (int n = 0; n < 2; ++n) {
          accK[m][n] = __builtin_amdgcn_mfma_f32_16x16x32_bf16(a[m], kb[n], accK[m][n], 0, 0, 0);
          accV[m][n] = __builtin_amdgcn_mfma_f32_16x16x32_bf16(a[m], vb[n], accV[m][n], 0, 0, 0);
        }
    }
    // per-batch epilogue: accumulate exp-weighted sums in registers
#pragma unroll
    for (int m = 0; m < 4; ++m)
#pragma unroll
      for (int n = 0; n < 2; ++n)
#pragma unroll
        for (int r = 0; r < 4; ++r) {
          float nmr = __expf(accK[m][n][r] + bkc[n] + wbc[n]);
          sumN[m][n][r] += nmr;
          sumWV[m][n][r] += nmr * (accV[m][n][r] + bvc[n]);
        }
  }

  // C/D layout: col = lane&15, row = (lane>>4)*4 + r
#pragma unroll
  for (int m = 0; m < 4; ++m)
#pragma unroll
    for (int n = 0; n < 2; ++n)
#pragma unroll
      for (int r = 0; r < 4; ++r) {
        int t = t0 + wrow * 64 + m * 16 + (lane >> 4) * 4 + r;
        int h = h0 + wcol * 32 + n * 16 + (lane & 15);
        weighted[(size_t)t * H_ + h] = sumWV[m][n][r] / sumN[m][n][r];
      }
}

// K2: Q GEMM + sigmoid(Q)*weighted epilogue. M = B*T flattened rows.
__global__ __launch_bounds__(256, 3) void q_kernel(
    const ushort* __restrict__ xb, const ushort* __restrict__ Wqb,
    const float* __restrict__ bq, const float* __restrict__ weighted,
    float* __restrict__ out) {
  __shared__ ushort As[128 * 32];
  __shared__ ushort Bs[128 * 32];

  const int tid = threadIdx.x;
  const int lane = tid & 63;
  const int w = tid >> 6;     // 0..3
  const int wrow = w >> 1;    // 0..1
  const int wcol = w & 1;     // 0..1
  const int h0 = blockIdx.x * 128;
  const int R0 = blockIdx.y * 128;  // row tile over B*T (never crosses batch: T%128==0)

  const int srow = tid >> 2;        // 0..63
  const int scol = (tid & 3) * 8;

  const int arow = wrow * 64 + (lane & 15);
  const int brow = wcol * 64 + (lane & 15);
  const int koff = (lane >> 4) * 8;

  floatx4 acc[4][4] = {};

  for (int kt = 0; kt < D_; kt += 32) {
    __syncthreads();
    GLOAD16(xb + (size_t)(R0 + srow) * D_ + kt + scol, As + tid * 8);
    GLOAD16(xb + (size_t)(R0 + 64 + srow) * D_ + kt + scol, As + (tid + 256) * 8);
    GLOAD16(Wqb + (size_t)(h0 + srow) * D_ + kt + scol, Bs + tid * 8);
    GLOAD16(Wqb + (size_t)(h0 + 64 + srow) * D_ + kt + scol, Bs + (tid + 256) * 8);
    __syncthreads();

    short8 a[4], bb[4];
#pragma unroll
    for (int m = 0; m < 4; ++m)
      a[m] = *(const short8*)&As[(arow + m * 16) * 32 + koff];
#pragma unroll
    for (int n = 0; n < 4; ++n)
      bb[n] = *(const short8*)&Bs[(brow + n * 16) * 32 + koff];
#pragma unroll
    for (int m = 0; m < 4; ++m)
#pragma unroll
      for (int n = 0; n < 4; ++n)
        acc[m][n] = __builtin_amdgcn_mfma_f32_16x16x32_bf16(a[m], bb[n], acc[m][n], 0, 0, 0);
  }

  float bqc[4];
#pragma unroll
  for (int n = 0; n < 4; ++n)
    bqc[n] = bq[h0 + wcol * 64 + n * 16 + (lane & 15)];

#pragma unroll
  for (int m = 0; m < 4; ++m)
#pragma unroll
    for (int n = 0; n < 4; ++n)
#pragma unroll
      for (int r = 0; r < 4; ++r) {
        int row = R0 + wrow * 64 + m * 16 + (lane >> 4) * 4 + r;
        int t = row & (T_ - 1);
        int h = h0 + wcol * 64 + n * 16 + (lane & 15);
        float q = acc[m][n][r] + bqc[n];
        float sig = 1.f / (1.f + __expf(-q));
        out[(size_t)row * H_ + h] = sig * weighted[(size_t)t * H_ + h];
      }
}

extern "C" void kernel_launch(void* const* d_in, const int* in_sizes, int n_in,
                              void* d_out, int out_size, void* d_ws, size_t ws_size,
                              hipStream_t stream) {
  (void)in_sizes; (void)n_in; (void)out_size; (void)ws_size;
  const float* x = (const float*)d_in[0];
  const float* Wq = (const float*)d_in[1];
  const float* bq = (const float*)d_in[2];
  const float* Wk = (const float*)d_in[3];
  const float* bk = (const float*)d_in[4];
  const float* Wv = (const float*)d_in[5];
  const float* bv = (const float*)d_in[6];
  const float* wbias = (const float*)d_in[7];
  float* out = (float*)d_out;

  char* ws = (char*)d_ws;
  const size_t XN = (size_t)B_ * T_ * D_;   // 33,554,432
  const size_t WN = (size_t)H_ * D_;        // 1,048,576
  ushort* xb  = (ushort*)ws;                         // 64 MiB
  ushort* Wqb = (ushort*)(ws + XN * 2);              // 2 MiB
  ushort* Wkb = Wqb + WN;                            // 2 MiB
  ushort* Wvb = Wkb + WN;                            // 2 MiB
  float* weighted = (float*)(ws + XN * 2 + 3 * WN * 2);  // 16 MiB

  cvt_kernel<<<2048, 256, 0, stream>>>(x, xb, (int)XN);
  cvt_kernel<<<512, 256, 0, stream>>>(Wq, Wqb, (int)WN);
  cvt_kernel<<<512, 256, 0, stream>>>(Wk, Wkb, (int)WN);
  cvt_kernel<<<512, 256, 0, stream>>>(Wv, Wvb, (int)WN);

  kv_kernel<<<dim3(H_ / 128, T_ / 128), 512, 0, stream>>>(xb, Wkb, Wvb, bk, bv, wbias, weighted);
  q_kernel<<<dim3(H_ / 128, (B_ * T_) / 128), 256, 0, stream>>>(xb, Wqb, bq, weighted, out);
}

// Round 2
// 351.545 us; speedup vs baseline: 1.1471x; 1.1471x over previous
//
#include <hip/hip_runtime.h>
#include <hip/hip_bf16.h>

#define B_ 8
#define T_ 4096
#define D_ 1024
#define H_ 1024

typedef __attribute__((ext_vector_type(8))) short short8;
typedef __attribute__((ext_vector_type(4))) float floatx4;

#define GLOAD16(gptr, lptr) \
  __builtin_amdgcn_global_load_lds((const __attribute__((address_space(1))) void*)(gptr), \
                                   (__attribute__((address_space(3))) void*)(lptr), 16, 0, 0)

__device__ __forceinline__ ushort f2b(float f) {
  unsigned x = __builtin_bit_cast(unsigned, f);
  unsigned r = (x + 0x7fffu + ((x >> 16) & 1u)) >> 16;  // RNE, inputs finite
  return (ushort)r;
}

__global__ void cvt_kernel(const float* __restrict__ in, ushort* __restrict__ out, int n) {
  int idx = blockIdx.x * blockDim.x + threadIdx.x;
  int stride = gridDim.x * blockDim.x;
  for (long i = (long)idx * 8; i < n; i += (long)stride * 8) {
    const float4 f0 = *(const float4*)(in + i);
    const float4 f1 = *(const float4*)(in + i + 4);
    union { ushort u[8]; uint4 v; } r;
    r.u[0] = f2b(f0.x); r.u[1] = f2b(f0.y); r.u[2] = f2b(f0.z); r.u[3] = f2b(f0.w);
    r.u[4] = f2b(f1.x); r.u[5] = f2b(f1.y); r.u[6] = f2b(f1.z); r.u[7] = f2b(f1.w);
    *(uint4*)(out + i) = r.v;
  }
}

// K1: fused K/V GEMM + batch reduction.
// Tile = 128 t-rows x 64 h-cols -> grid 16x64 = 512 blocks = 2 blocks/CU
// (4 waves/SIMD). Double-buffered LDS, ONE barrier per K-step.
// Loops b=0..7 with register-resident sumN/sumWV, writes weighted = sumWV/sumN.
__global__ __launch_bounds__(512, 4) void kv_kernel(
    const ushort* __restrict__ xb, const ushort* __restrict__ Wkb,
    const ushort* __restrict__ Wvb, const float* __restrict__ bk,
    const float* __restrict__ bv, const float* __restrict__ wbias,
    float* __restrict__ weighted) {
  __shared__ ushort As[2][128 * 32];  // 8 KiB each
  __shared__ ushort Ks[2][64 * 32];   // 4 KiB each
  __shared__ ushort Vs[2][64 * 32];   // 4 KiB each

  const int tid = threadIdx.x;
  const int lane = tid & 63;
  const int w = tid >> 6;       // 0..7
  const int wrow = w >> 1;      // 0..3  (32-row granule)
  const int wcol = w & 1;       // 0..1  (32-col granule)
  const int h0 = blockIdx.x * 64;
  const int t0 = blockIdx.y * 128;

  // staging: As = 512 slots of 16B (slot=tid); Ks/Vs = 256 slots each
  // (waves 0-3 -> Ks, waves 4-7 -> Vs). LDS dest is uniform-base + lane*16. ✓
  const int sArow = tid >> 2;          // 0..127
  const int sKrow = (tid & 255) >> 2;  // 0..63
  const int scol = (tid & 3) * 8;

  // fragment addressing (mfma_f32_16x16x32_bf16):
  // A: row = lane&15 (+m*16), k = (lane>>4)*8 + j ; B: col = lane&15 (+n*16)
  const int arow = wrow * 32 + (lane & 15);
  const int bcol = wcol * 32 + (lane & 15);  // + n*16
  const int koff = (lane >> 4) * 8;

  float wbc[2], bkc[2], bvc[2];
#pragma unroll
  for (int n = 0; n < 2; ++n) {
    int h = h0 + wcol * 32 + n * 16 + (lane & 15);
    wbc[n] = wbias[h];
    bkc[n] = bk[h];
    bvc[n] = bv[h];
  }

  const ushort* xsrc = xb + ((size_t)t0 + sArow) * D_ + scol;
  const ushort* ksrc = Wkb + ((size_t)h0 + sKrow) * D_ + scol;
  const ushort* vsrc = Wvb + ((size_t)h0 + sKrow) * D_ + scol;

  auto stage = [&](int step, int buf) {
    const int b = step >> 5;
    const int kt = (step & 31) << 5;
    GLOAD16(xsrc + (size_t)b * (T_ * D_) + kt, &As[buf][tid * 8]);
    if (w < 4) GLOAD16(ksrc + kt, &Ks[buf][tid * 8]);          // wave-uniform branch
    else       GLOAD16(vsrc + kt, &Vs[buf][(tid - 256) * 8]);
  };

  floatx4 accK[2][2] = {};
  floatx4 accV[2][2] = {};
  floatx4 sumN[2][2] = {};
  floatx4 sumWV[2][2] = {};

  stage(0, 0);
  __syncthreads();

  for (int step = 0; step < B_ * 32; ++step) {
    const int cur = step & 1;
    if (step + 1 < B_ * 32) stage(step + 1, cur ^ 1);  // prefetch into other buf

    short8 a[2], kb[2], vb[2];
#pragma unroll
    for (int m = 0; m < 2; ++m)
      a[m] = *(const short8*)&As[cur][(arow + m * 16) * 32 + koff];
#pragma unroll
    for (int n = 0; n < 2; ++n) {
      kb[n] = *(const short8*)&Ks[cur][(bcol + n * 16) * 32 + koff];
      vb[n] = *(const short8*)&Vs[cur][(bcol + n * 16) * 32 + koff];
    }
#pragma unroll
    for (int m = 0; m < 2; ++m)
#pragma unroll
      for (int n = 0; n < 2; ++n) {
        accK[m][n] = __builtin_amdgcn_mfma_f32_16x16x32_bf16(a[m], kb[n], accK[m][n], 0, 0, 0);
        accV[m][n] = __builtin_amdgcn_mfma_f32_16x16x32_bf16(a[m], vb[n], accV[m][n], 0, 0, 0);
      }

    if ((step & 31) == 31) {  // end of batch b: fold into exp-weighted sums
#pragma unroll
      for (int m = 0; m < 2; ++m)
#pragma unroll
        for (int n = 0; n < 2; ++n) {
#pragma unroll
          for (int r = 0; r < 4; ++r) {
            float nmr = __expf(accK[m][n][r] + bkc[n] + wbc[n]);
            sumN[m][n][r] += nmr;
            sumWV[m][n][r] += nmr * (accV[m][n][r] + bvc[n]);
          }
          accK[m][n] = floatx4{0.f, 0.f, 0.f, 0.f};
          accV[m][n] = floatx4{0.f, 0.f, 0.f, 0.f};
        }
    }
    __syncthreads();  // next buf staged + everyone done reading cur
  }

  // C/D layout: col = lane&15, row = (lane>>4)*4 + r
#pragma unroll
  for (int m = 0; m < 2; ++m)
#pragma unroll
    for (int n = 0; n < 2; ++n)
#pragma unroll
      for (int r = 0; r < 4; ++r) {
        int t = t0 + wrow * 32 + m * 16 + (lane >> 4) * 4 + r;
        int h = h0 + wcol * 32 + n * 16 + (lane & 15);
        weighted[(size_t)t * H_ + h] = sumWV[m][n][r] / sumN[m][n][r];
      }
}

// K2: Q GEMM + sigmoid(Q)*weighted epilogue. M = B*T flattened rows.
// 128x128 tile, double-buffered LDS, one barrier per K-step.
__global__ __launch_bounds__(256, 3) void q_kernel(
    const ushort* __restrict__ xb, const ushort* __restrict__ Wqb,
    const float* __restrict__ bq, const float* __restrict__ weighted,
    float* __restrict__ out) {
  __shared__ ushort As[2][128 * 32];
  __shared__ ushort Bs[2][128 * 32];

  const int tid = threadIdx.x;
  const int lane = tid & 63;
  const int w = tid >> 6;     // 0..3
  const int wrow = w >> 1;    // 0..1
  const int wcol = w & 1;     // 0..1
  const int h0 = blockIdx.x * 128;
  const int R0 = blockIdx.y * 128;  // row tile over B*T (T%128==0, no batch crossing)

  const int srow = tid >> 2;        // 0..63
  const int scol = (tid & 3) * 8;

  const int arow = wrow * 64 + (lane & 15);
  const int brow = wcol * 64 + (lane & 15);
  const int koff = (lane >> 4) * 8;

  const ushort* xsrc = xb + ((size_t)R0 + srow) * D_ + scol;
  const ushort* wsrc = Wqb + ((size_t)h0 + srow) * D_ + scol;

  auto stage = [&](int kt, int buf) {
    GLOAD16(xsrc + kt, &As[buf][tid * 8]);
    GLOAD16(xsrc + (size_t)64 * D_ + kt, &As[buf][(tid + 256) * 8]);
    GLOAD16(wsrc + kt, &Bs[buf][tid * 8]);
    GLOAD16(wsrc + (size_t)64 * D_ + kt, &Bs[buf][(tid + 256) * 8]);
  };

  floatx4 acc[4][4] = {};

  stage(0, 0);
  __syncthreads();

  for (int it = 0; it < D_ / 32; ++it) {
    const int cur = it & 1;
    if (it + 1 < D_ / 32) stage((it + 1) * 32, cur ^ 1);

    short8 a[4], bb[4];
#pragma unroll
    for (int m = 0; m < 4; ++m)
      a[m] = *(const short8*)&As[cur][(arow + m * 16) * 32 + koff];
#pragma unroll
    for (int n = 0; n < 4; ++n)
      bb[n] = *(const short8*)&Bs[cur][(brow + n * 16) * 32 + koff];
#pragma unroll
    for (int m = 0; m < 4; ++m)
#pragma unroll
      for (int n = 0; n < 4; ++n)
        acc[m][n] = __builtin_amdgcn_mfma_f32_16x16x32_bf16(a[m], bb[n], acc[m][n], 0, 0, 0);
    __syncthreads();
  }

  float bqc[4];
#pragma unroll
  for (int n = 0; n < 4; ++n)
    bqc[n] = bq[h0 + wcol * 64 + n * 16 + (lane & 15)];

#pragma unroll
  for (int m = 0; m < 4; ++m)
#pragma unroll
    for (int n = 0; n < 4; ++n)
#pragma unroll
      for (int r = 0; r < 4; ++r) {
        int row = R0 + wrow * 64 + m * 16 + (lane >> 4) * 4 + r;
        int t = row & (T_ - 1);
        int h = h0 + wcol * 64 + n * 16 + (lane & 15);
        float q = acc[m][n][r] + bqc[n];
        float sig = 1.f / (1.f + __expf(-q));
        out[(size_t)row * H_ + h] = sig * weighted[(size_t)t * H_ + h];
      }
}

extern "C" void kernel_launch(void* const* d_in, const int* in_sizes, int n_in,
                              void* d_out, int out_size, void* d_ws, size_t ws_size,
                              hipStream_t stream) {
  (void)in_sizes; (void)n_in; (void)out_size; (void)ws_size;
  const float* x = (const float*)d_in[0];
  const float* Wq = (const float*)d_in[1];
  const float* bq = (const float*)d_in[2];
  const float* Wk = (const float*)d_in[3];
  const float* bk = (const float*)d_in[4];
  const float* Wv = (const float*)d_in[5];
  const float* bv = (const float*)d_in[6];
  const float* wbias = (const float*)d_in[7];
  float* out = (float*)d_out;

  char* ws = (char*)d_ws;
  const size_t XN = (size_t)B_ * T_ * D_;   // 33,554,432
  const size_t WN = (size_t)H_ * D_;        // 1,048,576
  ushort* xb  = (ushort*)ws;                         // 64 MiB
  ushort* Wqb = (ushort*)(ws + XN * 2);              // 2 MiB
  ushort* Wkb = Wqb + WN;                            // 2 MiB
  ushort* Wvb = Wkb + WN;                            // 2 MiB
  float* weighted = (float*)(ws + XN * 2 + 3 * WN * 2);  // 16 MiB

  cvt_kernel<<<2048, 256, 0, stream>>>(x, xb, (int)XN);
  cvt_kernel<<<512, 256, 0, stream>>>(Wq, Wqb, (int)WN);
  cvt_kernel<<<512, 256, 0, stream>>>(Wk, Wkb, (int)WN);
  cvt_kernel<<<512, 256, 0, stream>>>(Wv, Wvb, (int)WN);

  kv_kernel<<<dim3(H_ / 64, T_ / 128), 512, 0, stream>>>(xb, Wkb, Wvb, bk, bv, wbias, weighted);
  q_kernel<<<dim3(H_ / 128, (B_ * T_) / 128), 256, 0, stream>>>(xb, Wqb, bq, weighted, out);
}

// Round 3
// 296.049 us; speedup vs baseline: 1.3621x; 1.1875x over previous
//
#include <hip/hip_runtime.h>
#include <hip/hip_bf16.h>

#define B_ 8
#define T_ 4096
#define D_ 1024
#define H_ 1024

typedef __attribute__((ext_vector_type(8))) short short8;
typedef __attribute__((ext_vector_type(4))) float floatx4;

#define GLOAD16(gptr, lptr) \
  __builtin_amdgcn_global_load_lds((const __attribute__((address_space(1))) void*)(gptr), \
                                   (__attribute__((address_space(3))) void*)(lptr), 16, 0, 0)

__device__ __forceinline__ ushort f2b(float f) {
  unsigned x = __builtin_bit_cast(unsigned, f);
  unsigned r = (x + 0x7fffu + ((x >> 16) & 1u)) >> 16;  // RNE, inputs finite
  return (ushort)r;
}

__global__ void cvt_kernel(const float* __restrict__ in, ushort* __restrict__ out, int n) {
  int idx = blockIdx.x * blockDim.x + threadIdx.x;
  int stride = gridDim.x * blockDim.x;
  for (long i = (long)idx * 8; i < n; i += (long)stride * 8) {
    const float4 f0 = *(const float4*)(in + i);
    const float4 f1 = *(const float4*)(in + i + 4);
    union { ushort u[8]; uint4 v; } r;
    r.u[0] = f2b(f0.x); r.u[1] = f2b(f0.y); r.u[2] = f2b(f0.z); r.u[3] = f2b(f0.w);
    r.u[4] = f2b(f1.x); r.u[5] = f2b(f1.y); r.u[6] = f2b(f1.z); r.u[7] = f2b(f1.w);
    *(uint4*)(out + i) = r.v;
  }
}

// K1: fused K/V GEMM + batch reduction.
// Block = 4 waves (2t x 2h), wave tile 64t x 32h (m=4, n=2), block tile 128t x 64h.
// K-phase = 64 (dbuf, one barrier/phase, 128 phases = 8 batches x 16).
// LDS tiles swizzled: chunk' = chunk ^ (row&7)  (16B chunks, 8 per 128B row)
// -> fragment ds_read_b128 is 2-way (free) instead of 16-way.
// Swizzle applied on BOTH sides: pre-swizzled global source (global_load_lds
// writes linearly) and swizzled read offsets (same involution).
__global__ __launch_bounds__(256, 2) void kv_kernel(
    const ushort* __restrict__ xb, const ushort* __restrict__ Wkb,
    const ushort* __restrict__ Wvb, const float* __restrict__ bk,
    const float* __restrict__ bv, const float* __restrict__ wbias,
    float* __restrict__ weighted) {
  __shared__ ushort As[2][128 * 64];  // 16 KiB each
  __shared__ ushort Ks[2][64 * 64];   // 8 KiB each
  __shared__ ushort Vs[2][64 * 64];   // 8 KiB each

  const int tid = threadIdx.x;
  const int lane = tid & 63;
  const int w = tid >> 6;       // 0..3
  const int wrow = w >> 1;      // 0..1  (64-row granule)
  const int wcol = w & 1;       // 0..1  (32-col granule)
  const int t0 = blockIdx.x * 128;  // grid.x = t => same-A blocks share XCD
  const int h0 = blockIdx.y * 64;

  // staging: thread covers 16B chunk addr16 = it*256 + tid of each tile.
  // row = it*32 + (tid>>3), phys chunk = tid&7. Source logical chunk =
  // phys ^ (row&7) = (tid&7) ^ ((tid>>3)&7)  (it*32 = 0 mod 8).
  const int sr = tid >> 3;                       // 0..31 (row within 32-group)
  const int swz = (tid & 7) ^ ((tid >> 3) & 7);  // source chunk (per-thread const)

  // fragment addressing (mfma_f32_16x16x32_bf16):
  // A: row = arow + m*16, k-chunk(16B) logical = s*4 + (lane>>4)
  // phys chunk = logical ^ (row&7) = logical ^ (lane&7)  (invariant in m).
  const int arow = wrow * 64 + (lane & 15);
  const int bcol = wcol * 32 + (lane & 15);
  const int cs0 = ((lane >> 4) + 0) ^ (lane & 7);  // sub 0
  const int cs1 = ((lane >> 4) + 4) ^ (lane & 7);  // sub 1

  float wbc[2], bkc[2], bvc[2];
#pragma unroll
  for (int n = 0; n < 2; ++n) {
    int h = h0 + wcol * 32 + n * 16 + (lane & 15);
    wbc[n] = wbias[h];
    bkc[n] = bk[h];
    bvc[n] = bv[h];
  }

  const ushort* ksb = Wkb + (size_t)h0 * D_ + (size_t)sr * D_ + swz * 8;
  const ushort* vsb = Wvb + (size_t)h0 * D_ + (size_t)sr * D_ + swz * 8;
  const ushort* xsb = xb + (size_t)t0 * D_ + (size_t)sr * D_ + swz * 8;

  auto stage = [&](int p, int nb) {
    const int b = p >> 4;
    const int kt = (p & 15) << 6;
    const ushort* xs = xsb + (size_t)b * (T_ * D_) + kt;
#pragma unroll
    for (int it = 0; it < 4; ++it)
      GLOAD16(xs + (size_t)(it * 32) * D_, &As[nb][(it * 256 + tid) * 8]);
#pragma unroll
    for (int it = 0; it < 2; ++it) {
      GLOAD16(ksb + kt + (size_t)(it * 32) * D_, &Ks[nb][(it * 256 + tid) * 8]);
      GLOAD16(vsb + kt + (size_t)(it * 32) * D_, &Vs[nb][(it * 256 + tid) * 8]);
    }
  };

  floatx4 accK[4][2] = {};
  floatx4 accV[4][2] = {};
  floatx4 sumN[4][2] = {};
  floatx4 sumWV[4][2] = {};

  stage(0, 0);
  __syncthreads();

  for (int p = 0; p < 128; ++p) {
    const int cur = p & 1;
    if (p + 1 < 128) stage(p + 1, cur ^ 1);  // prefetch into other buf

#pragma unroll
    for (int s = 0; s < 2; ++s) {
      const int cs = s ? cs1 : cs0;
      short8 a[4], kb[2], vb[2];
#pragma unroll
      for (int m = 0; m < 4; ++m)
        a[m] = *(const short8*)&As[cur][(arow + m * 16) * 64 + cs * 8];
#pragma unroll
      for (int n = 0; n < 2; ++n) {
        kb[n] = *(const short8*)&Ks[cur][(bcol + n * 16) * 64 + cs * 8];
        vb[n] = *(const short8*)&Vs[cur][(bcol + n * 16) * 64 + cs * 8];
      }
#pragma unroll
      for (int m = 0; m < 4; ++m)
#pragma unroll
        for (int n = 0; n < 2; ++n) {
          accK[m][n] = __builtin_amdgcn_mfma_f32_16x16x32_bf16(a[m], kb[n], accK[m][n], 0, 0, 0);
          accV[m][n] = __builtin_amdgcn_mfma_f32_16x16x32_bf16(a[m], vb[n], accV[m][n], 0, 0, 0);
        }
    }

    if ((p & 15) == 15) {  // end of batch: fold into exp-weighted sums
#pragma unroll
      for (int m = 0; m < 4; ++m)
#pragma unroll
        for (int n = 0; n < 2; ++n) {
#pragma unroll
          for (int r = 0; r < 4; ++r) {
            float nmr = __expf(accK[m][n][r] + bkc[n] + wbc[n]);
            sumN[m][n][r] += nmr;
            sumWV[m][n][r] += nmr * (accV[m][n][r] + bvc[n]);
          }
          accK[m][n] = floatx4{0.f, 0.f, 0.f, 0.f};
          accV[m][n] = floatx4{0.f, 0.f, 0.f, 0.f};
        }
    }
    __syncthreads();
  }

  // C/D layout: col = lane&15, row = (lane>>4)*4 + r
#pragma unroll
  for (int m = 0; m < 4; ++m)
#pragma unroll
    for (int n = 0; n < 2; ++n)
#pragma unroll
      for (int r = 0; r < 4; ++r) {
        int t = t0 + wrow * 64 + m * 16 + (lane >> 4) * 4 + r;
        int h = h0 + wcol * 32 + n * 16 + (lane & 15);
        weighted[(size_t)t * H_ + h] = sumWV[m][n][r] / sumN[m][n][r];
      }
}

// K2: Q GEMM + sigmoid(Q)*weighted epilogue. M = B*T flattened rows.
// 128x128 tile, dbuf, one barrier per K-step. Swizzle: [row][32] tiles,
// 4 chunks/row, chunk' = chunk ^ ((row>>1)&3) -> 2-way ds_read_b128.
__global__ __launch_bounds__(256, 3) void q_kernel(
    const ushort* __restrict__ xb, const ushort* __restrict__ Wqb,
    const float* __restrict__ bq, const float* __restrict__ weighted,
    float* __restrict__ out) {
  __shared__ ushort As[2][128 * 32];
  __shared__ ushort Bs[2][128 * 32];

  const int tid = threadIdx.x;
  const int lane = tid & 63;
  const int w = tid >> 6;     // 0..3
  const int wrow = w >> 1;    // 0..1
  const int wcol = w & 1;     // 0..1
  const int R0 = blockIdx.x * 128;  // grid.x = rows => same-A blocks share XCD
  const int h0 = blockIdx.y * 128;

  // staging chunk addr16 = tid (+256): row = (tid>>2) (+64), phys chunk = tid&3,
  // source chunk = phys ^ ((row>>1)&3) = (tid&3) ^ ((tid>>3)&3)  (64 = 0 mod 4 after >>1).
  const int srow = tid >> 2;
  const int sq = (tid & 3) ^ ((tid >> 3) & 3);

  const int arow = wrow * 64 + (lane & 15);
  const int brow = wcol * 64 + (lane & 15);
  const int cq = (lane >> 4) ^ ((lane >> 1) & 3);  // phys chunk (invariant in m)

  const ushort* xsrc = xb + ((size_t)R0 + srow) * D_ + sq * 8;
  const ushort* wsrc = Wqb + ((size_t)h0 + srow) * D_ + sq * 8;

  auto stage = [&](int kt, int buf) {
    GLOAD16(xsrc + kt, &As[buf][tid * 8]);
    GLOAD16(xsrc + (size_t)64 * D_ + kt, &As[buf][(tid + 256) * 8]);
    GLOAD16(wsrc + kt, &Bs[buf][tid * 8]);
    GLOAD16(wsrc + (size_t)64 * D_ + kt, &Bs[buf][(tid + 256) * 8]);
  };

  floatx4 acc[4][4] = {};

  stage(0, 0);
  __syncthreads();

  for (int it = 0; it < D_ / 32; ++it) {
    const int cur = it & 1;
    if (it + 1 < D_ / 32) stage((it + 1) * 32, cur ^ 1);

    short8 a[4], bb[4];
#pragma unroll
    for (int m = 0; m < 4; ++m)
      a[m] = *(const short8*)&As[cur][(arow + m * 16) * 32 + cq * 8];
#pragma unroll
    for (int n = 0; n < 4; ++n)
      bb[n] = *(const short8*)&Bs[cur][(brow + n * 16) * 32 + cq * 8];
#pragma unroll
    for (int m = 0; m < 4; ++m)
#pragma unroll
      for (int n = 0; n < 4; ++n)
        acc[m][n] = __builtin_amdgcn_mfma_f32_16x16x32_bf16(a[m], bb[n], acc[m][n], 0, 0, 0);
    __syncthreads();
  }

  float bqc[4];
#pragma unroll
  for (int n = 0; n < 4; ++n)
    bqc[n] = bq[h0 + wcol * 64 + n * 16 + (lane & 15)];

#pragma unroll
  for (int m = 0; m < 4; ++m)
#pragma unroll
    for (int n = 0; n < 4; ++n)
#pragma unroll
      for (int r = 0; r < 4; ++r) {
        int row = R0 + wrow * 64 + m * 16 + (lane >> 4) * 4 + r;
        int t = row & (T_ - 1);
        int h = h0 + wcol * 64 + n * 16 + (lane & 15);
        float q = acc[m][n][r] + bqc[n];
        float sig = 1.f / (1.f + __expf(-q));
        out[(size_t)row * H_ + h] = sig * weighted[(size_t)t * H_ + h];
      }
}

extern "C" void kernel_launch(void* const* d_in, const int* in_sizes, int n_in,
                              void* d_out, int out_size, void* d_ws, size_t ws_size,
                              hipStream_t stream) {
  (void)in_sizes; (void)n_in; (void)out_size; (void)ws_size;
  const float* x = (const float*)d_in[0];
  const float* Wq = (const float*)d_in[1];
  const float* bq = (const float*)d_in[2];
  const float* Wk = (const float*)d_in[3];
  const float* bk = (const float*)d_in[4];
  const float* Wv = (const float*)d_in[5];
  const float* bv = (const float*)d_in[6];
  const float* wbias = (const float*)d_in[7];
  float* out = (float*)d_out;

  char* ws = (char*)d_ws;
  const size_t XN = (size_t)B_ * T_ * D_;   // 33,554,432
  const size_t WN = (size_t)H_ * D_;        // 1,048,576
  ushort* xb  = (ushort*)ws;                         // 64 MiB
  ushort* Wqb = (ushort*)(ws + XN * 2);              // 2 MiB
  ushort* Wkb = Wqb + WN;                            // 2 MiB
  ushort* Wvb = Wkb + WN;                            // 2 MiB
  float* weighted = (float*)(ws + XN * 2 + 3 * WN * 2);  // 16 MiB

  cvt_kernel<<<2048, 256, 0, stream>>>(x, xb, (int)XN);
  cvt_kernel<<<512, 256, 0, stream>>>(Wq, Wqb, (int)WN);
  cvt_kernel<<<512, 256, 0, stream>>>(Wk, Wkb, (int)WN);
  cvt_kernel<<<512, 256, 0, stream>>>(Wv, Wvb, (int)WN);

  kv_kernel<<<dim3(T_ / 128, H_ / 64), 256, 0, stream>>>(xb, Wkb, Wvb, bk, bv, wbias, weighted);
  q_kernel<<<dim3((B_ * T_) / 128, H_ / 128), 256, 0, stream>>>(xb, Wqb, bq, weighted, out);
}

// Round 4
// 285.029 us; speedup vs baseline: 1.4148x; 1.0387x over previous
//
#include <hip/hip_runtime.h>
#include <hip/hip_bf16.h>

#define B_ 8
#define T_ 4096
#define D_ 1024
#define H_ 1024

typedef __attribute__((ext_vector_type(8))) short short8;
typedef __attribute__((ext_vector_type(4))) float floatx4;

#define GLOAD16(gptr, lptr) \
  __builtin_amdgcn_global_load_lds((const __attribute__((address_space(1))) void*)(gptr), \
                                   (__attribute__((address_space(3))) void*)(lptr), 16, 0, 0)

__device__ __forceinline__ ushort f2b(float f) {
  unsigned x = __builtin_bit_cast(unsigned, f);
  unsigned r = (x + 0x7fffu + ((x >> 16) & 1u)) >> 16;  // RNE, inputs finite
  return (ushort)r;
}

__global__ void cvt_kernel(const float* __restrict__ in, ushort* __restrict__ out, int n) {
  int idx = blockIdx.x * blockDim.x + threadIdx.x;
  int stride = gridDim.x * blockDim.x;
  for (long i = (long)idx * 8; i < n; i += (long)stride * 8) {
    const float4 f0 = *(const float4*)(in + i);
    const float4 f1 = *(const float4*)(in + i + 4);
    union { ushort u[8]; uint4 v; } r;
    r.u[0] = f2b(f0.x); r.u[1] = f2b(f0.y); r.u[2] = f2b(f0.z); r.u[3] = f2b(f0.w);
    r.u[4] = f2b(f1.x); r.u[5] = f2b(f1.y); r.u[6] = f2b(f1.z); r.u[7] = f2b(f1.w);
    *(uint4*)(out + i) = r.v;
  }
}

// K1: fused K/V GEMM + batch reduction.
// Block = 8 waves (4t x 2h), wave tile 64t x 32h (m4 n2), block tile 256t x 64h.
// Triple-buffered LDS (144 KiB dynamic), counted vmcnt(6) + raw s_barrier:
// phase p stages p+2, waits only for p+1's loads -> loads stay in flight
// across barriers (T3+T4). T5 setprio around MFMA clusters.
// Swizzle (both sides): 16B chunk' = chunk ^ (row&7); reads 2-way (free).
__global__ __launch_bounds__(512, 2) void kv_kernel(
    const ushort* __restrict__ xb, const ushort* __restrict__ Wkb,
    const ushort* __restrict__ Wvb, const float* __restrict__ bk,
    const float* __restrict__ bv, const float* __restrict__ wbias,
    float* __restrict__ weighted) {
  extern __shared__ ushort lds[];
  ushort* const AsB = lds;              // 3 bufs x 256x64 = 3x16384 elems
  ushort* const KsB = lds + 49152;      // 3 bufs x 64x64  = 3x4096
  ushort* const VsB = lds + 61440;      // 3 bufs x 64x64  = 3x4096

  const int tid = threadIdx.x;
  const int lane = tid & 63;
  const int w = tid >> 6;       // 0..7
  const int wrow = w >> 1;      // 0..3  (64-row granule)
  const int wcol = w & 1;       // 0..1  (32-col granule)
  const int t0 = blockIdx.x * 256;  // grid.x = t: same-t blocks share XCD (x reuse)
  const int h0 = blockIdx.y * 64;

  // staging: chunk idx = it*512 + tid (A) / tid (K,V); row = idx>>3, phys = idx&7,
  // source logical chunk = phys ^ (row&7) = (tid&7) ^ ((tid>>3)&7).
  const int srow = tid >> 3;
  const int swz = (tid & 7) ^ ((tid >> 3) & 7);

  const int arow = wrow * 64 + (lane & 15);
  const int bcol = wcol * 32 + (lane & 15);
  const int cs0 = (lane >> 4) ^ (lane & 7);        // k-sub 0 phys chunk
  const int cs1 = ((lane >> 4) + 4) ^ (lane & 7);  // k-sub 1

  float wbc[2], bkc[2], bvc[2];
#pragma unroll
  for (int n = 0; n < 2; ++n) {
    int h = h0 + wcol * 32 + n * 16 + (lane & 15);
    wbc[n] = wbias[h];
    bkc[n] = bk[h];
    bvc[n] = bv[h];
  }

  const ushort* xsb = xb + (size_t)(t0 + srow) * D_ + swz * 8;
  const ushort* ksb = Wkb + (size_t)(h0 + srow) * D_ + swz * 8;
  const ushort* vsb = Wvb + (size_t)(h0 + srow) * D_ + swz * 8;

  auto stage = [&](int p, int nb) {  // 6 loads/thread
    const int b = p >> 4;
    const int kt = (p & 15) << 6;
    const ushort* xs = xsb + (size_t)b * (T_ * D_) + kt;
    ushort* Ab = AsB + nb * 16384;
#pragma unroll
    for (int it = 0; it < 4; ++it)
      GLOAD16(xs + (size_t)(it * 64) * D_, Ab + (it * 512 + tid) * 8);
    GLOAD16(ksb + kt, KsB + nb * 4096 + tid * 8);
    GLOAD16(vsb + kt, VsB + nb * 4096 + tid * 8);
  };

  floatx4 accK[4][2] = {};
  floatx4 accV[4][2] = {};
  floatx4 sumN[4][2] = {};
  floatx4 sumWV[4][2] = {};

  stage(0, 0);
  stage(1, 1);
  asm volatile("s_waitcnt vmcnt(6)" ::: "memory");  // stage(0) landed
  __builtin_amdgcn_s_barrier();

  int cur = 0, stg = 2;
  for (int p = 0; p < 128; ++p) {
    if (p < 126) stage(p + 2, stg);

    const ushort* Ac = AsB + cur * 16384;
    const ushort* Kc = KsB + cur * 4096;
    const ushort* Vc = VsB + cur * 4096;
#pragma unroll
    for (int s = 0; s < 2; ++s) {
      const int cs = s ? cs1 : cs0;
      short8 a[4], kb2[2], vb2[2];
#pragma unroll
      for (int m = 0; m < 4; ++m)
        a[m] = *(const short8*)&Ac[(arow + m * 16) * 64 + cs * 8];
#pragma unroll
      for (int n = 0; n < 2; ++n) {
        kb2[n] = *(const short8*)&Kc[(bcol + n * 16) * 64 + cs * 8];
        vb2[n] = *(const short8*)&Vc[(bcol + n * 16) * 64 + cs * 8];
      }
      __builtin_amdgcn_s_setprio(1);
#pragma unroll
      for (int m = 0; m < 4; ++m)
#pragma unroll
        for (int n = 0; n < 2; ++n) {
          accK[m][n] = __builtin_amdgcn_mfma_f32_16x16x32_bf16(a[m], kb2[n], accK[m][n], 0, 0, 0);
          accV[m][n] = __builtin_amdgcn_mfma_f32_16x16x32_bf16(a[m], vb2[n], accV[m][n], 0, 0, 0);
        }
      __builtin_amdgcn_s_setprio(0);
    }

    if ((p & 15) == 15) {  // end of batch: fold into exp-weighted sums
#pragma unroll
      for (int m = 0; m < 4; ++m)
#pragma unroll
        for (int n = 0; n < 2; ++n) {
#pragma unroll
          for (int r = 0; r < 4; ++r) {
            float nmr = __expf(accK[m][n][r] + bkc[n] + wbc[n]);
            sumN[m][n][r] += nmr;
            sumWV[m][n][r] += nmr * (accV[m][n][r] + bvc[n]);
          }
          accK[m][n] = floatx4{0.f, 0.f, 0.f, 0.f};
          accV[m][n] = floatx4{0.f, 0.f, 0.f, 0.f};
        }
    }

    if (p < 126) { asm volatile("s_waitcnt vmcnt(6)" ::: "memory"); }
    else         { asm volatile("s_waitcnt vmcnt(0)" ::: "memory"); }
    __builtin_amdgcn_s_barrier();
    cur = (cur == 2) ? 0 : cur + 1;
    stg = (stg == 2) ? 0 : stg + 1;
  }

  // C/D layout: col = lane&15, row = (lane>>4)*4 + r
#pragma unroll
  for (int m = 0; m < 4; ++m)
#pragma unroll
    for (int n = 0; n < 2; ++n)
#pragma unroll
      for (int r = 0; r < 4; ++r) {
        int t = t0 + wrow * 64 + m * 16 + (lane >> 4) * 4 + r;
        int h = h0 + wcol * 32 + n * 16 + (lane & 15);
        weighted[(size_t)t * H_ + h] = sumWV[m][n][r] / sumN[m][n][r];
      }
}

// K2: Q GEMM + sigmoid(Q)*weighted epilogue. 256r x 128h tile, 8 waves
// (wave 64x64 m4 n4), triple-buffered 72 KiB LDS, counted vmcnt(3).
// Swizzle: 4 chunks/row, chunk' = chunk ^ ((row>>1)&3).
__global__ __launch_bounds__(512, 2) void q_kernel(
    const ushort* __restrict__ xb, const ushort* __restrict__ Wqb,
    const float* __restrict__ bq, const float* __restrict__ weighted,
    float* __restrict__ out) {
  extern __shared__ ushort lds[];
  ushort* const AsB = lds;              // 3 bufs x 256x32 = 3x8192
  ushort* const BsB = lds + 24576;      // 3 bufs x 128x32 = 3x4096

  const int tid = threadIdx.x;
  const int lane = tid & 63;
  const int w = tid >> 6;     // 0..7
  const int wrow = w >> 1;    // 0..3
  const int wcol = w & 1;     // 0..1
  const int R0 = blockIdx.x * 256;  // rows over B*T (T%256==0: no batch crossing)
  const int h0 = blockIdx.y * 128;

  const int srow = tid >> 2;
  const int sq = (tid & 3) ^ ((tid >> 3) & 3);

  const int arow = wrow * 64 + (lane & 15);
  const int brow = wcol * 64 + (lane & 15);
  const int cq = (lane >> 4) ^ (((lane & 15) >> 1) & 3);

  const ushort* xsrc = xb + (size_t)(R0 + srow) * D_ + sq * 8;
  const ushort* wsrc = Wqb + (size_t)(h0 + srow) * D_ + sq * 8;

  auto stage = [&](int kt, int nb) {  // 3 loads/thread
    GLOAD16(xsrc + kt, AsB + nb * 8192 + tid * 8);
    GLOAD16(xsrc + (size_t)128 * D_ + kt, AsB + nb * 8192 + (tid + 512) * 8);
    GLOAD16(wsrc + kt, BsB + nb * 4096 + tid * 8);
  };

  floatx4 acc[4][4] = {};

  stage(0, 0);
  stage(32, 1);
  asm volatile("s_waitcnt vmcnt(3)" ::: "memory");
  __builtin_amdgcn_s_barrier();

  int cur = 0, stg = 2;
  for (int it = 0; it < 32; ++it) {
    if (it < 30) stage((it + 2) * 32, stg);

    const ushort* Ac = AsB + cur * 8192;
    const ushort* Bc = BsB + cur * 4096;
    short8 a[4], bb[4];
#pragma unroll
    for (int m = 0; m < 4; ++m)
      a[m] = *(const short8*)&Ac[(arow + m * 16) * 32 + cq * 8];
#pragma unroll
    for (int n = 0; n < 4; ++n)
      bb[n] = *(const short8*)&Bc[(brow + n * 16) * 32 + cq * 8];
    __builtin_amdgcn_s_setprio(1);
#pragma unroll
    for (int m = 0; m < 4; ++m)
#pragma unroll
      for (int n = 0; n < 4; ++n)
        acc[m][n] = __builtin_amdgcn_mfma_f32_16x16x32_bf16(a[m], bb[n], acc[m][n], 0, 0, 0);
    __builtin_amdgcn_s_setprio(0);

    if (it < 30) { asm volatile("s_waitcnt vmcnt(3)" ::: "memory"); }
    else         { asm volatile("s_waitcnt vmcnt(0)" ::: "memory"); }
    __builtin_amdgcn_s_barrier();
    cur = (cur == 2) ? 0 : cur + 1;
    stg = (stg == 2) ? 0 : stg + 1;
  }

  float bqc[4];
#pragma unroll
  for (int n = 0; n < 4; ++n)
    bqc[n] = bq[h0 + wcol * 64 + n * 16 + (lane & 15)];

#pragma unroll
  for (int m = 0; m < 4; ++m)
#pragma unroll
    for (int n = 0; n < 4; ++n)
#pragma unroll
      for (int r = 0; r < 4; ++r) {
        int row = R0 + wrow * 64 + m * 16 + (lane >> 4) * 4 + r;
        int t = row & (T_ - 1);
        int h = h0 + wcol * 64 + n * 16 + (lane & 15);
        float q = acc[m][n][r] + bqc[n];
        float sig = 1.f / (1.f + __expf(-q));
        out[(size_t)row * H_ + h] = sig * weighted[(size_t)t * H_ + h];
      }
}

extern "C" void kernel_launch(void* const* d_in, const int* in_sizes, int n_in,
                              void* d_out, int out_size, void* d_ws, size_t ws_size,
                              hipStream_t stream) {
  (void)in_sizes; (void)n_in; (void)out_size; (void)ws_size;
  const float* x = (const float*)d_in[0];
  const float* Wq = (const float*)d_in[1];
  const float* bq = (const float*)d_in[2];
  const float* Wk = (const float*)d_in[3];
  const float* bk = (const float*)d_in[4];
  const float* Wv = (const float*)d_in[5];
  const float* bv = (const float*)d_in[6];
  const float* wbias = (const float*)d_in[7];
  float* out = (float*)d_out;

  char* ws = (char*)d_ws;
  const size_t XN = (size_t)B_ * T_ * D_;   // 33,554,432
  const size_t WN = (size_t)H_ * D_;        // 1,048,576
  ushort* xb  = (ushort*)ws;                         // 64 MiB
  ushort* Wqb = (ushort*)(ws + XN * 2);              // 2 MiB
  ushort* Wkb = Wqb + WN;                            // 2 MiB
  ushort* Wvb = Wkb + WN;                            // 2 MiB
  float* weighted = (float*)(ws + XN * 2 + 3 * WN * 2);  // 16 MiB

  // allow >64 KiB dynamic LDS (no-op if already set; not a stream op)
  (void)hipFuncSetAttribute((const void*)kv_kernel,
                            hipFuncAttributeMaxDynamicSharedMemorySize, 147456);
  (void)hipFuncSetAttribute((const void*)q_kernel,
                            hipFuncAttributeMaxDynamicSharedMemorySize, 73728);

  cvt_kernel<<<2048, 256, 0, stream>>>(x, xb, (int)XN);
  cvt_kernel<<<512, 256, 0, stream>>>(Wq, Wqb, (int)WN);
  cvt_kernel<<<512, 256, 0, stream>>>(Wk, Wkb, (int)WN);
  cvt_kernel<<<512, 256, 0, stream>>>(Wv, Wvb, (int)WN);

  kv_kernel<<<dim3(T_ / 256, H_ / 64), 512, 147456, stream>>>(xb, Wkb, Wvb, bk, bv, wbias, weighted);
  q_kernel<<<dim3((B_ * T_) / 256, H_ / 128), 512, 73728, stream>>>(xb, Wqb, bq, weighted, out);
}